// Round 11
// baseline (357.384 us; speedup 1.0000x reference)
//
#include <hip/hip_runtime.h>
#include <cmath>

#define N_GRAPHS 64

typedef _Float16 f16x8 __attribute__((ext_vector_type(8)));
typedef _Float16 f16x4 __attribute__((ext_vector_type(4)));
typedef float f32x4 __attribute__((ext_vector_type(4)));

// ---------------------------------------------------------------------------
// Counting sort of edges by dst
// ---------------------------------------------------------------------------
__global__ __launch_bounds__(256) void build_hist(
    const int* __restrict__ dst, int* __restrict__ hist, int E)
{
    int i = blockIdx.x * 256 + threadIdx.x;
    if (i < E) atomicAdd(&hist[dst[i]], 1);
}

__global__ __launch_bounds__(1024) void scan_deg(
    const int* __restrict__ hist, int* __restrict__ cursor, int N)
{
    __shared__ int part[1024];
    int tid = threadIdx.x;
    int per = (N + 1023) / 1024;
    int base = tid * per;
    int s = 0;
    for (int i = 0; i < per; ++i) { int idx = base + i; if (idx < N) s += hist[idx]; }
    part[tid] = s;
    __syncthreads();
    for (int off = 1; off < 1024; off <<= 1) {
        int v = (tid >= off) ? part[tid - off] : 0;
        __syncthreads();
        part[tid] += v;
        __syncthreads();
    }
    int run = part[tid] - s;
    for (int i = 0; i < per; ++i) {
        int idx = base + i;
        if (idx < N) { cursor[idx] = run; run += hist[idx]; }
    }
}

__global__ __launch_bounds__(256) void scatter_edges(
    const int* __restrict__ src, const int* __restrict__ dst,
    int* __restrict__ cursor, int* __restrict__ ssrc, int* __restrict__ sdst, int E)
{
    int i = blockIdx.x * 256 + threadIdx.x;
    if (i >= E) return;
    int d = dst[i];
    int pos = atomicAdd(&cursor[d], 1);
    ssrc[pos] = src[i];
    sdst[pos] = d;
}

// ---------------------------------------------------------------------------
// W2 [K][N] fp32 -> W2T [N][K] f16
// ---------------------------------------------------------------------------
template<int H>
__global__ __launch_bounds__(256) void w2_to_t(
    const float* __restrict__ w2, _Float16* __restrict__ wt)
{
    int idx = blockIdx.x * 256 + threadIdx.x;
    if (idx >= H * H) return;
    int n = idx / H, k = idx % H;
    wt[idx] = (_Float16)w2[k * H + n];
}

// ---------------------------------------------------------------------------
// Fused P/Q weights: PQWT[j][k] (f16, B^T) = (W3_prev @ W1part_cur)^T
// ---------------------------------------------------------------------------
template<int K, int HOUT>
__global__ __launch_bounds__(256) void pqw_fuse(
    const float* __restrict__ w3, const float* __restrict__ w1,
    _Float16* __restrict__ pqwt)
{
    int idx = blockIdx.x * 256 + threadIdx.x;
    if (idx >= 2 * HOUT * K) return;
    int j = idx / K, k = idx % K;
    float acc = 0.f;
    if (j < HOUT) {
        for (int m = 0; m < K; ++m)
            acc += w3[k * K + m] * (w1[(size_t)m * HOUT + j] - w1[(size_t)(K + m) * HOUT + j]);
    } else {
        int jq = j - HOUT;
        for (int m = 0; m < K; ++m)
            acc += w3[k * K + m] * w1[(size_t)(K + m) * HOUT + jq];
    }
    pqwt[(size_t)j * K + k] = (_Float16)acc;
}

template<int K, int HOUT>
__global__ __launch_bounds__(256) void pqb_fuse(
    const float* __restrict__ w1, const float* __restrict__ b3,
    const float* __restrict__ b1, float* __restrict__ pb, float* __restrict__ bex)
{
    int j = blockIdx.x * 256 + threadIdx.x;
    if (j >= 2 * HOUT) return;
    float acc = 0.f;
    if (j < HOUT) {
        for (int m = 0; m < K; ++m)
            acc += b3[m] * (w1[(size_t)m * HOUT + j] - w1[(size_t)(K + m) * HOUT + j]);
        bex[j] = b1[j];
    } else {
        int jq = j - HOUT;
        for (int m = 0; m < K; ++m)
            acc += b3[m] * w1[(size_t)(K + m) * HOUT + jq];
        bex[j] = 0.f;
    }
    pb[j] = acc;
}

// ---------------------------------------------------------------------------
// conv1 P/Q from raw x (F=3)
// ---------------------------------------------------------------------------
template<int F, int H>
__global__ __launch_bounds__(256) void node_pqh(
    const float* __restrict__ x, const float* __restrict__ w1,
    const float* __restrict__ b1, _Float16* __restrict__ P,
    _Float16* __restrict__ Q, int nNodes)
{
    int idx = blockIdx.x * 256 + threadIdx.x;
    int total = nNodes * (H / 8);
    if (idx >= total) return;
    int n = idx / (H / 8), j8 = (idx % (H / 8)) * 8;
    float p[8], q[8];
#pragma unroll
    for (int j = 0; j < 8; ++j) { p[j] = b1[j8 + j]; q[j] = 0.f; }
    for (int k = 0; k < F; ++k) {
        float xv = x[(size_t)n * F + k];
        const float* wt = &w1[(size_t)k * H + j8];
        const float* wb = &w1[(size_t)(F + k) * H + j8];
        float4 t0 = *(const float4*)wt, t1 = *(const float4*)(wt + 4);
        float4 b0 = *(const float4*)wb, b1v = *(const float4*)(wb + 4);
        p[0] += xv * (t0.x - b0.x);  q[0] += xv * b0.x;
        p[1] += xv * (t0.y - b0.y);  q[1] += xv * b0.y;
        p[2] += xv * (t0.z - b0.z);  q[2] += xv * b0.z;
        p[3] += xv * (t0.w - b0.w);  q[3] += xv * b0.w;
        p[4] += xv * (t1.x - b1v.x); q[4] += xv * b1v.x;
        p[5] += xv * (t1.y - b1v.y); q[5] += xv * b1v.y;
        p[6] += xv * (t1.z - b1v.z); q[6] += xv * b1v.z;
        p[7] += xv * (t1.w - b1v.w); q[7] += xv * b1v.w;
    }
    f16x8 ph, qh;
#pragma unroll
    for (int j = 0; j < 8; ++j) { ph[j] = (_Float16)p[j]; qh[j] = (_Float16)q[j]; }
    *(f16x8*)&P[(size_t)n * H + j8] = ph;
    *(f16x8*)&Q[(size_t)n * H + j8] = qh;
}

// ---------------------------------------------------------------------------
// pq_gemm: [P|Q](f16) = f16GEMM(h2sum_prev, PQWT) + deg*pb + bex
// ---------------------------------------------------------------------------
template<int K, int HOUT>
__global__ __launch_bounds__(256) void pq_gemm(
    const float* __restrict__ h2sum, const _Float16* __restrict__ PQWT,
    const float* __restrict__ pb, const float* __restrict__ bex,
    const int* __restrict__ deg, _Float16* __restrict__ Ph,
    _Float16* __restrict__ Qh, int nNodes)
{
    constexpr int T = 64;
    constexpr int KCH = K / 8;
    constexpr int CPW = (2 * HOUT) / 4;
    constexpr int NFRAG = CPW / 16;
    constexpr int KSTEPS = K / 32;

    __shared__ _Float16 A[T * K];
    __shared__ int sdeg[T];

    const int tid = threadIdx.x;
    const int n0 = blockIdx.x * T;

    if (tid < T) { int n = n0 + tid; sdeg[tid] = (n < nNodes) ? deg[n] : 0; }

    for (int q = tid; q < T * KCH; q += 256) {
        int row = q / KCH, kc = q % KCH;
        int n = n0 + row; if (n >= nNodes) n = nNodes - 1;
        const float* hr = h2sum + (size_t)n * K + kc * 8;
        float4 a0 = *(const float4*)hr, a1 = *(const float4*)(hr + 4);
        f16x8 h;
        h[0] = (_Float16)a0.x; h[1] = (_Float16)a0.y;
        h[2] = (_Float16)a0.z; h[3] = (_Float16)a0.w;
        h[4] = (_Float16)a1.x; h[5] = (_Float16)a1.y;
        h[6] = (_Float16)a1.z; h[7] = (_Float16)a1.w;
        int byte = row * (2 * K) + kc * 16;
        byte ^= ((row & 7) << 4);
        *(f16x8*)((char*)A + byte) = h;
    }
    __syncthreads();

    const int wave = tid >> 6, lane = tid & 63;
    const int c0 = wave * CPW;
    const int lr = lane & 15;
    const int kg = lane >> 4;

    f32x4 acc[4][NFRAG];
#pragma unroll
    for (int m = 0; m < 4; ++m)
#pragma unroll
        for (int n = 0; n < NFRAG; ++n) acc[m][n] = (f32x4){0.f, 0.f, 0.f, 0.f};

    for (int ks = 0; ks < KSTEPS; ++ks) {
        const int k0 = ks * 32 + kg * 8;
        f16x8 af[4];
#pragma unroll
        for (int m = 0; m < 4; ++m) {
            int row = m * 16 + lr;
            int byte = row * (2 * K) + k0 * 2;
            byte ^= ((row & 7) << 4);
            af[m] = *(const f16x8*)((char*)A + byte);
        }
        f16x8 bf[NFRAG];
#pragma unroll
        for (int n = 0; n < NFRAG; ++n)
            bf[n] = *(const f16x8*)&PQWT[(size_t)(c0 + n * 16 + lr) * K + k0];
#pragma unroll
        for (int m = 0; m < 4; ++m)
#pragma unroll
            for (int n = 0; n < NFRAG; ++n)
                acc[m][n] = __builtin_amdgcn_mfma_f32_16x16x32_f16(af[m], bf[n], acc[m][n], 0, 0, 0);
    }

#pragma unroll
    for (int m = 0; m < 4; ++m)
#pragma unroll
        for (int n = 0; n < NFRAG; ++n) {
            int col = c0 + n * 16 + lr;
            float pbv = pb[col], bexv = bex[col];
            int row0 = m * 16 + kg * 4;
#pragma unroll
            for (int j = 0; j < 4; ++j) {
                int row = row0 + j;
                int node = n0 + row;
                if (node < nNodes) {
                    float v = acc[m][n][j] + (float)sdeg[row] * pbv + bexv;
                    if (col < HOUT) Ph[(size_t)node * HOUT + col] = (_Float16)v;
                    else            Qh[(size_t)node * HOUT + col - HOUT] = (_Float16)v;
                }
            }
        }
}

// ---------------------------------------------------------------------------
// Persistent edge kernel (all convs): each block owns MAXT consecutive
// 64-edge tiles; its wave's W2T column-slice lives in REGISTERS (loaded once).
// Per tile: gather->LDS, barrier, MFMA (LDS A x reg B - zero global loads),
// hoisted relu, ballot segmented reduce, barrier.
// NBLK chosen so breg+acc fit the VGPR budget (512/NBLK... 2 waves/SIMD=256).
// ---------------------------------------------------------------------------
template<int H, int NBLK, int MAXT>
__global__ __launch_bounds__(256, NBLK) void edge_persist(
    const _Float16* __restrict__ P, const _Float16* __restrict__ Q,
    const int* __restrict__ ssrc, const int* __restrict__ sdst,
    const _Float16* __restrict__ W2T, const float* __restrict__ b2,
    float* __restrict__ h2sum, int nE, int ntiles)
{
    constexpr int T = 64;
    constexpr int KCH = H / 8;             // f16x8 chunks per row
    constexpr int ITER = (T * KCH) / 256;  // staging chunks per thread
    constexpr int NFRAG = H / 64;          // 16-col fragments per wave
    constexpr int KSTEPS = H / 32;
    static_assert(H % 64 == 0 && ITER >= 1, "geometry");

    __shared__ _Float16 A[T * H];
    __shared__ int s_dst[MAXT * T];
    __shared__ int s_src[MAXT * T];

    // bijective XCD-chunked swizzle (consecutive dst ranges -> same XCD L2)
    int bid;
    {
        int b = blockIdx.x, nb = gridDim.x;
        int q = nb >> 3, r = nb & 7;
        int xcd = b & 7, idx = b >> 3;
        bid = (xcd < r) ? xcd * (q + 1) + idx
                        : r * (q + 1) + (xcd - r) * q + idx;
    }

    const int tid = threadIdx.x;
    const int t0 = bid * MAXT;
    int cnt = ntiles - t0; if (cnt > MAXT) cnt = MAXT;
    if (cnt <= 0) return;
    const int e0 = t0 * T;

    for (int j = tid; j < cnt * T; j += 256) {
        int e = e0 + j; if (e >= nE) e = nE - 1;
        s_dst[j] = sdst[e];
        s_src[j] = ssrc[e];
    }

    const int wave = tid >> 6, lane = tid & 63;
    const int c0 = wave * (H / 4);
    const int lr = lane & 15;
    const int kg = lane >> 4;

    float bias[NFRAG];
#pragma unroll
    for (int n = 0; n < NFRAG; ++n) bias[n] = b2[c0 + n * 16 + lr];

    // wave's B slice -> registers, once per block
    f16x8 breg[KSTEPS][NFRAG];
#pragma unroll
    for (int ks = 0; ks < KSTEPS; ++ks)
#pragma unroll
        for (int n = 0; n < NFRAG; ++n)
            breg[ks][n] = *(const f16x8*)&W2T[(size_t)(c0 + n * 16 + lr) * H + ks * 32 + kg * 8];

    __syncthreads();   // indices staged

    for (int li = 0; li < cnt; ++li) {
        const int* sd = &s_dst[li * T];
        const int* ss = &s_src[li * T];
        int nvalid = nE - (e0 + li * T); if (nvalid > T) nvalid = T;

        // gather + h1 = relu(P[dst]+Q[src]) -> swizzled A (short liveness)
#pragma unroll 2
        for (int it = 0; it < ITER; ++it) {
            int q = tid + it * 256;
            int row = q / KCH, kc = q % KCH;
            f16x8 pv = *(const f16x8*)&P[(size_t)sd[row] * H + kc * 8];
            f16x8 qv = *(const f16x8*)&Q[(size_t)ss[row] * H + kc * 8];
            f16x8 h;
#pragma unroll
            for (int j = 0; j < 8; ++j) {
                _Float16 v = pv[j] + qv[j];
                h[j] = v > (_Float16)0.f ? v : (_Float16)0.f;
            }
            int byte = row * (2 * H) + kc * 16;
            byte ^= ((row & 7) << 4);
            *(f16x8*)((char*)A + byte) = h;
        }
        __syncthreads();

        // MFMA: h2_pre = h1 @ W2 + b2  (A from LDS, B from registers)
        f32x4 acc[4][NFRAG];
#pragma unroll
        for (int n = 0; n < NFRAG; ++n)
#pragma unroll
            for (int m = 0; m < 4; ++m)
                acc[m][n] = (f32x4){bias[n], bias[n], bias[n], bias[n]};

#pragma unroll
        for (int ks = 0; ks < KSTEPS; ++ks) {
            const int k0 = ks * 32 + kg * 8;
            f16x8 af[4];
#pragma unroll
            for (int m = 0; m < 4; ++m) {
                int row = m * 16 + lr;
                int byte = row * (2 * H) + k0 * 2;
                byte ^= ((row & 7) << 4);
                af[m] = *(const f16x8*)((const char*)A + byte);
            }
#pragma unroll
            for (int m = 0; m < 4; ++m)
#pragma unroll
                for (int n = 0; n < NFRAG; ++n)
                    acc[m][n] = __builtin_amdgcn_mfma_f32_16x16x32_f16(af[m], breg[ks][n], acc[m][n], 0, 0, 0);
        }

        // hoisted relu
#pragma unroll
        for (int m = 0; m < 4; ++m)
#pragma unroll
            for (int n = 0; n < NFRAG; ++n)
#pragma unroll
                for (int j = 0; j < 4; ++j)
                    acc[m][n][j] = fmaxf(acc[m][n][j], 0.f);

        // segment boundary mask (wave-uniform)
        unsigned long long mask;
        {
            int t = lane;
            int dt = sd[t];
            int dn = sd[(t + 1) & 63];
            bool last = (t + 1 >= nvalid) || (dt != dn);
            mask = __ballot(last);
        }

        int r = 0;
        while (r < nvalid) {
            unsigned long long m2 = mask >> r;
            int len = (int)__ffsll((long long)m2);
            int rend = r + len;
            int d = sd[r];

            float part[NFRAG];
#pragma unroll
            for (int n = 0; n < NFRAG; ++n) part[n] = 0.f;

#pragma unroll
            for (int m = 0; m < 4; ++m) {
                int mlo = m * 16, mhi = mlo + 16;
                if (rend <= mlo || r >= mhi) continue;
                if (r <= mlo && rend >= mhi) {
#pragma unroll
                    for (int n = 0; n < NFRAG; ++n)
#pragma unroll
                        for (int j = 0; j < 4; ++j)
                            part[n] += acc[m][n][j];
                } else {
#pragma unroll
                    for (int j = 0; j < 4; ++j) {
                        int row = mlo + kg * 4 + j;
                        bool in = (row >= r) && (row < rend);
#pragma unroll
                        for (int n = 0; n < NFRAG; ++n)
                            part[n] += in ? acc[m][n][j] : 0.f;
                    }
                }
            }
#pragma unroll
            for (int n = 0; n < NFRAG; ++n) {
                part[n] += __shfl_xor(part[n], 16);
                part[n] += __shfl_xor(part[n], 32);
            }
            if (kg == 0) {
#pragma unroll
                for (int n = 0; n < NFRAG; ++n)
                    atomicAdd(&h2sum[(size_t)d * H + c0 + n * 16 + lr], part[n]);
            }
            r = rend;
        }
        __syncthreads();   // reduce done before next gather overwrites A
    }
}

// ---------------------------------------------------------------------------
// Parallel pool: 40 nodes per block, segmented by (sorted) batch, atomics.
// ---------------------------------------------------------------------------
__global__ __launch_bounds__(256) void pool_part(
    const float* __restrict__ h2s3, const int* __restrict__ batch,
    const int* __restrict__ cursor, float* __restrict__ gsumh,
    float* __restrict__ gcnt, float* __restrict__ gdeg, int nNodes)
{
    constexpr int NPB = 40;
    __shared__ int sb[NPB];
    int n0 = blockIdx.x * NPB;
    int nn = nNodes - n0; if (nn > NPB) nn = NPB;
    if (nn <= 0) return;
    if (threadIdx.x < nn) sb[threadIdx.x] = batch[n0 + threadIdx.x];
    __syncthreads();
    int c = threadIdx.x;
    int g = sb[0];
    float a = 0.f;
    for (int i = 0; i < nn; ++i) {
        int gg = sb[i];
        if (gg != g) { atomicAdd(&gsumh[(size_t)g * 256 + c], a); a = 0.f; g = gg; }
        a += h2s3[(size_t)(n0 + i) * 256 + c];
    }
    atomicAdd(&gsumh[(size_t)g * 256 + c], a);
    if (c == 0) {
        int start = 0;
        for (int i = 1; i <= nn; ++i) {
            if (i == nn || sb[i] != sb[start]) {
                int gs = sb[start];
                atomicAdd(&gcnt[gs], (float)(i - start));
                int eEnd = cursor[n0 + i - 1];
                int eStart = (n0 + start > 0) ? cursor[n0 + start - 1] : 0;
                atomicAdd(&gdeg[gs], (float)(eEnd - eStart));
                start = i;
            }
        }
    }
}

// ---------------------------------------------------------------------------
// Head: one block per graph.
// ---------------------------------------------------------------------------
__global__ __launch_bounds__(256) void head64(
    const float* __restrict__ gsumh, const float* __restrict__ gcnt,
    const float* __restrict__ gdeg, const float* __restrict__ w3,
    const float* __restrict__ b3, const float* __restrict__ l2w,
    const float* __restrict__ l2b, const float* __restrict__ l3w,
    const float* __restrict__ l3b, float* __restrict__ out)
{
    __shared__ float gh[256];
    __shared__ float gm[256];
    __shared__ float hp[4][64];
    __shared__ float hv[64];
    int g = blockIdx.x, tid = threadIdx.x;
    gh[tid] = gsumh[(size_t)g * 256 + tid];
    __syncthreads();
    float dg = gdeg[g], cnt = fmaxf(gcnt[g], 1.f);
    float acc = dg * b3[tid];
#pragma unroll 4
    for (int k = 0; k < 256; ++k) acc += gh[k] * w3[(size_t)k * 256 + tid];
    gm[tid] = acc / cnt;
    __syncthreads();
    int c = tid & 63, q = tid >> 6;
    float a2 = 0.f;
#pragma unroll 4
    for (int kk = 0; kk < 64; ++kk) {
        int k = q * 64 + kk;
        a2 += gm[k] * l2w[(size_t)k * 64 + c];
    }
    hp[q][c] = a2;
    __syncthreads();
    if (tid < 64) hv[tid] = hp[0][tid] + hp[1][tid] + hp[2][tid] + hp[3][tid] + l2b[tid];
    __syncthreads();
    if (tid < 2) {
        float a3 = l3b[tid];
#pragma unroll 4
        for (int k = 0; k < 64; ++k) a3 += hv[k] * l3w[k * 2 + tid];
        out[g * 2 + tid] = 1.f / (1.f + expf(-a3));
    }
}

// ---------------------------------------------------------------------------
extern "C" void kernel_launch(void* const* d_in, const int* in_sizes, int n_in,
                              void* d_out, int out_size, void* d_ws, size_t ws_size,
                              hipStream_t stream)
{
    const float* x     = (const float*)d_in[0];
    const int*   ei    = (const int*)d_in[1];
    const int*   batch = (const int*)d_in[2];
    const float* c1_w1 = (const float*)d_in[3];
    const float* c1_b1 = (const float*)d_in[4];
    const float* c1_w2 = (const float*)d_in[5];
    const float* c1_b2 = (const float*)d_in[6];
    const float* c1_w3 = (const float*)d_in[7];
    const float* c1_b3 = (const float*)d_in[8];
    const float* c2_w1 = (const float*)d_in[9];
    const float* c2_b1 = (const float*)d_in[10];
    const float* c2_w2 = (const float*)d_in[11];
    const float* c2_b2 = (const float*)d_in[12];
    const float* c2_w3 = (const float*)d_in[13];
    const float* c2_b3 = (const float*)d_in[14];
    const float* c3_w1 = (const float*)d_in[15];
    const float* c3_b1 = (const float*)d_in[16];
    const float* c3_w2 = (const float*)d_in[17];
    const float* c3_b2 = (const float*)d_in[18];
    const float* c3_w3 = (const float*)d_in[19];
    const float* c3_b3 = (const float*)d_in[20];
    const float* l2w   = (const float*)d_in[21];
    const float* l2b   = (const float*)d_in[22];
    const float* l3w   = (const float*)d_in[23];
    const float* l3b   = (const float*)d_in[24];
    float* out = (float*)d_out;

    const int N = in_sizes[0] / 3;
    const int E = in_sizes[1] / 2;
    const int* src = ei;
    const int* dst = ei + E;

    // workspace layout — zeroed region first
    float* h2s1 = (float*)d_ws;                          // N*64
    float* h2s2 = h2s1 + (size_t)N * 64;                 // N*128
    float* h2s3 = h2s2 + (size_t)N * 128;                // N*256
    int*   hist = (int*)(h2s3 + (size_t)N * 256);        // N (deg)
    float* gsumh = (float*)(hist + N);                   // 64*256
    float* gcnt  = gsumh + (size_t)N_GRAPHS * 256;       // 64
    float* gdeg  = gcnt + N_GRAPHS;                      // 64  -- zero ends here
    int*   cursor = (int*)(gdeg + N_GRAPHS);             // N
    int*   ssrcb  = cursor + N;                          // E
    int*   sdstb  = ssrcb + E;                           // E
    _Float16* Ph  = (_Float16*)(sdstb + E);              // N*256 f16 (max H)
    _Float16* Qh  = Ph + (size_t)N * 256;                // N*256 f16
    _Float16* wt  = Qh + (size_t)N * 256;                // 256*256 f16
    _Float16* pqwt2 = wt + 256 * 256;                    // 256*64 f16
    _Float16* pqwt3 = pqwt2 + 256 * 64;                  // 512*128 f16
    float* pb2   = (float*)(pqwt3 + 512 * 128);          // 256
    float* bex2  = pb2 + 256;                            // 256
    float* pb3   = bex2 + 256;                           // 512
    float* bex3  = pb3 + 512;                            // 512

    size_t zero_bytes = (size_t)N * (64 + 128 + 256) * sizeof(float)
                      + (size_t)N * sizeof(int)
                      + ((size_t)N_GRAPHS * 256 + 2 * N_GRAPHS) * sizeof(float);
    hipMemsetAsync(h2s1, 0, zero_bytes, stream);

    // sort edges by dst
    build_hist<<<(E + 255) / 256, 256, 0, stream>>>(dst, hist, E);
    scan_deg<<<1, 1024, 0, stream>>>(hist, cursor, N);
    scatter_edges<<<(E + 255) / 256, 256, 0, stream>>>(src, dst, cursor, ssrcb, sdstb, E);

    // fused P/Q weights for conv2 and conv3
    pqw_fuse<64, 128><<<(2 * 128 * 64 + 255) / 256, 256, 0, stream>>>(c1_w3, c2_w1, pqwt2);
    pqb_fuse<64, 128><<<(2 * 128 + 255) / 256, 256, 0, stream>>>(c2_w1, c1_b3, c2_b1, pb2, bex2);
    pqw_fuse<128, 256><<<(2 * 256 * 128 + 255) / 256, 256, 0, stream>>>(c2_w3, c3_w1, pqwt3);
    pqb_fuse<128, 256><<<(2 * 256 + 255) / 256, 256, 0, stream>>>(c3_w1, c2_b3, c3_b1, pb3, bex3);

    const int ntiles = (E + 63) / 64;
    const int NB = (N + 63) / 64;

    // conv1: 3 -> 64   (breg 8 VGPR; 4 blocks/CU; grid ~1000)
    node_pqh<3, 64><<<(N * 8 + 255) / 256, 256, 0, stream>>>(x, c1_w1, c1_b1, Ph, Qh, N);
    w2_to_t<64><<<(64 * 64 + 255) / 256, 256, 0, stream>>>(c1_w2, wt);
    edge_persist<64, 4, 5><<<(ntiles + 4) / 5, 256, 0, stream>>>(
        Ph, Qh, ssrcb, sdstb, wt, c1_b2, h2s1, E, ntiles);

    // conv2: 64 -> 128  (breg 32 VGPR; 3 blocks/CU; grid ~715)
    pq_gemm<64, 128><<<NB, 256, 0, stream>>>(h2s1, pqwt2, pb2, bex2, hist, Ph, Qh, N);
    w2_to_t<128><<<(128 * 128 + 255) / 256, 256, 0, stream>>>(c2_w2, wt);
    edge_persist<128, 3, 7><<<(ntiles + 6) / 7, 256, 0, stream>>>(
        Ph, Qh, ssrcb, sdstb, wt, c2_b2, h2s2, E, ntiles);

    // conv3: 128 -> 256  (breg 128 VGPR; 2 blocks/CU -> 256 VGPR cap; grid 500)
    pq_gemm<128, 256><<<NB, 256, 0, stream>>>(h2s2, pqwt3, pb3, bex3, hist, Ph, Qh, N);
    w2_to_t<256><<<(256 * 256 + 255) / 256, 256, 0, stream>>>(c3_w2, wt);
    edge_persist<256, 2, 10><<<(ntiles + 9) / 10, 256, 0, stream>>>(
        Ph, Qh, ssrcb, sdstb, wt, c3_b2, h2s3, E, ntiles);

    // pool + head
    pool_part<<<(N + 39) / 40, 256, 0, stream>>>(h2s3, batch, cursor, gsumh, gcnt, gdeg, N);
    head64<<<N_GRAPHS, 256, 0, stream>>>(gsumh, gcnt, gdeg, c3_w3, c3_b3, l2w, l2b, l3w, l3b, out);
}

// Round 12
// 287.828 us; speedup vs baseline: 1.2417x; 1.2417x over previous
//
#include <hip/hip_runtime.h>
#include <cmath>

#define N_GRAPHS 64

typedef _Float16 f16x8 __attribute__((ext_vector_type(8)));
typedef _Float16 f16x4 __attribute__((ext_vector_type(4)));
typedef float f32x4 __attribute__((ext_vector_type(4)));

// ---------------------------------------------------------------------------
// Counting sort of edges by dst
// ---------------------------------------------------------------------------
__global__ __launch_bounds__(256) void build_hist(
    const int* __restrict__ dst, int* __restrict__ hist, int E)
{
    int i = blockIdx.x * 256 + threadIdx.x;
    if (i < E) atomicAdd(&hist[dst[i]], 1);
}

__global__ __launch_bounds__(1024) void scan_deg(
    const int* __restrict__ hist, int* __restrict__ cursor, int N)
{
    __shared__ int part[1024];
    int tid = threadIdx.x;
    int per = (N + 1023) / 1024;
    int base = tid * per;
    int s = 0;
    for (int i = 0; i < per; ++i) { int idx = base + i; if (idx < N) s += hist[idx]; }
    part[tid] = s;
    __syncthreads();
    for (int off = 1; off < 1024; off <<= 1) {
        int v = (tid >= off) ? part[tid - off] : 0;
        __syncthreads();
        part[tid] += v;
        __syncthreads();
    }
    int run = part[tid] - s;
    for (int i = 0; i < per; ++i) {
        int idx = base + i;
        if (idx < N) { cursor[idx] = run; run += hist[idx]; }
    }
}

__global__ __launch_bounds__(256) void scatter_edges(
    const int* __restrict__ src, const int* __restrict__ dst,
    int* __restrict__ cursor, int* __restrict__ ssrc, int* __restrict__ sdst, int E)
{
    int i = blockIdx.x * 256 + threadIdx.x;
    if (i >= E) return;
    int d = dst[i];
    int pos = atomicAdd(&cursor[d], 1);
    ssrc[pos] = src[i];
    sdst[pos] = d;
}

// ---------------------------------------------------------------------------
// ONE fused weight-prep kernel: wt1/wt2/wt3 transposes + fused P/Q weights
// and biases for conv2/conv3. Segments over a flat index space.
// ---------------------------------------------------------------------------
__global__ __launch_bounds__(256) void prep_all(
    const float* __restrict__ c1w2, const float* __restrict__ c2w2,
    const float* __restrict__ c3w2, const float* __restrict__ c1w3,
    const float* __restrict__ c2w1, const float* __restrict__ c1b3,
    const float* __restrict__ c2b1, const float* __restrict__ c2w3,
    const float* __restrict__ c3w1, const float* __restrict__ c2b3,
    const float* __restrict__ c3b1,
    _Float16* __restrict__ wt1, _Float16* __restrict__ wt2,
    _Float16* __restrict__ wt3, _Float16* __restrict__ pqwt2,
    _Float16* __restrict__ pqwt3, float* __restrict__ pb2,
    float* __restrict__ bex2, float* __restrict__ pb3,
    float* __restrict__ bex3)
{
    int idx = blockIdx.x * 256 + threadIdx.x;
    if (idx < 4096) {                       // wt1: c1_w2^T (64x64)
        int n = idx >> 6, k = idx & 63;
        wt1[idx] = (_Float16)c1w2[k * 64 + n];
        return;
    }
    idx -= 4096;
    if (idx < 16384) {                      // wt2: c2_w2^T (128x128)
        int n = idx >> 7, k = idx & 127;
        wt2[idx] = (_Float16)c2w2[k * 128 + n];
        return;
    }
    idx -= 16384;
    if (idx < 65536) {                      // wt3: c3_w2^T (256x256)
        int n = idx >> 8, k = idx & 255;
        wt3[idx] = (_Float16)c3w2[k * 256 + n];
        return;
    }
    idx -= 65536;
    if (idx < 16384) {                      // pqwt2: j in [0,256), k in [0,64)
        int j = idx >> 6, k = idx & 63;
        float acc = 0.f;
        if (j < 128) {
            for (int m = 0; m < 64; ++m)
                acc += c1w3[k * 64 + m] * (c2w1[m * 128 + j] - c2w1[(64 + m) * 128 + j]);
        } else {
            int jq = j - 128;
            for (int m = 0; m < 64; ++m)
                acc += c1w3[k * 64 + m] * c2w1[(64 + m) * 128 + jq];
        }
        pqwt2[idx] = (_Float16)acc;
        return;
    }
    idx -= 16384;
    if (idx < 65536) {                      // pqwt3: j in [0,512), k in [0,128)
        int j = idx >> 7, k = idx & 127;
        float acc = 0.f;
        if (j < 256) {
            for (int m = 0; m < 128; ++m)
                acc += c2w3[k * 128 + m] * (c3w1[m * 256 + j] - c3w1[(128 + m) * 256 + j]);
        } else {
            int jq = j - 256;
            for (int m = 0; m < 128; ++m)
                acc += c2w3[k * 128 + m] * c3w1[(128 + m) * 256 + jq];
        }
        pqwt3[idx] = (_Float16)acc;
        return;
    }
    idx -= 65536;
    if (idx < 256) {                        // pb2/bex2: j in [0,256)
        int j = idx;
        float acc = 0.f;
        if (j < 128) {
            for (int m = 0; m < 64; ++m)
                acc += c1b3[m] * (c2w1[m * 128 + j] - c2w1[(64 + m) * 128 + j]);
            bex2[j] = c2b1[j];
        } else {
            int jq = j - 128;
            for (int m = 0; m < 64; ++m)
                acc += c1b3[m] * c2w1[(64 + m) * 128 + jq];
            bex2[j] = 0.f;
        }
        pb2[j] = acc;
        return;
    }
    idx -= 256;
    if (idx < 512) {                        // pb3/bex3: j in [0,512)
        int j = idx;
        float acc = 0.f;
        if (j < 256) {
            for (int m = 0; m < 128; ++m)
                acc += c2b3[m] * (c3w1[m * 256 + j] - c3w1[(128 + m) * 256 + j]);
            bex3[j] = c3b1[j];
        } else {
            int jq = j - 256;
            for (int m = 0; m < 128; ++m)
                acc += c2b3[m] * c3w1[(128 + m) * 256 + jq];
            bex3[j] = 0.f;
        }
        pb3[j] = acc;
        return;
    }
}

// ---------------------------------------------------------------------------
// conv1 P/Q from raw x (F=3)
// ---------------------------------------------------------------------------
template<int F, int H>
__global__ __launch_bounds__(256) void node_pqh(
    const float* __restrict__ x, const float* __restrict__ w1,
    const float* __restrict__ b1, _Float16* __restrict__ P,
    _Float16* __restrict__ Q, int nNodes)
{
    int idx = blockIdx.x * 256 + threadIdx.x;
    int total = nNodes * (H / 8);
    if (idx >= total) return;
    int n = idx / (H / 8), j8 = (idx % (H / 8)) * 8;
    float p[8], q[8];
#pragma unroll
    for (int j = 0; j < 8; ++j) { p[j] = b1[j8 + j]; q[j] = 0.f; }
    for (int k = 0; k < F; ++k) {
        float xv = x[(size_t)n * F + k];
        const float* wt = &w1[(size_t)k * H + j8];
        const float* wb = &w1[(size_t)(F + k) * H + j8];
        float4 t0 = *(const float4*)wt, t1 = *(const float4*)(wt + 4);
        float4 b0 = *(const float4*)wb, b1v = *(const float4*)(wb + 4);
        p[0] += xv * (t0.x - b0.x);  q[0] += xv * b0.x;
        p[1] += xv * (t0.y - b0.y);  q[1] += xv * b0.y;
        p[2] += xv * (t0.z - b0.z);  q[2] += xv * b0.z;
        p[3] += xv * (t0.w - b0.w);  q[3] += xv * b0.w;
        p[4] += xv * (t1.x - b1v.x); q[4] += xv * b1v.x;
        p[5] += xv * (t1.y - b1v.y); q[5] += xv * b1v.y;
        p[6] += xv * (t1.z - b1v.z); q[6] += xv * b1v.z;
        p[7] += xv * (t1.w - b1v.w); q[7] += xv * b1v.w;
    }
    f16x8 ph, qh;
#pragma unroll
    for (int j = 0; j < 8; ++j) { ph[j] = (_Float16)p[j]; qh[j] = (_Float16)q[j]; }
    *(f16x8*)&P[(size_t)n * H + j8] = ph;
    *(f16x8*)&Q[(size_t)n * H + j8] = qh;
}

// ---------------------------------------------------------------------------
// pq_gemm: [P|Q](f16) = f16GEMM(h2sum_prev, PQWT) + deg*pb + bex
// ---------------------------------------------------------------------------
template<int K, int HOUT>
__global__ __launch_bounds__(256) void pq_gemm(
    const float* __restrict__ h2sum, const _Float16* __restrict__ PQWT,
    const float* __restrict__ pb, const float* __restrict__ bex,
    const int* __restrict__ deg, _Float16* __restrict__ Ph,
    _Float16* __restrict__ Qh, int nNodes)
{
    constexpr int T = 64;
    constexpr int KCH = K / 8;
    constexpr int CPW = (2 * HOUT) / 4;
    constexpr int NFRAG = CPW / 16;
    constexpr int KSTEPS = K / 32;

    __shared__ _Float16 A[T * K];
    __shared__ int sdeg[T];

    const int tid = threadIdx.x;
    const int n0 = blockIdx.x * T;

    if (tid < T) { int n = n0 + tid; sdeg[tid] = (n < nNodes) ? deg[n] : 0; }

    for (int q = tid; q < T * KCH; q += 256) {
        int row = q / KCH, kc = q % KCH;
        int n = n0 + row; if (n >= nNodes) n = nNodes - 1;
        const float* hr = h2sum + (size_t)n * K + kc * 8;
        float4 a0 = *(const float4*)hr, a1 = *(const float4*)(hr + 4);
        f16x8 h;
        h[0] = (_Float16)a0.x; h[1] = (_Float16)a0.y;
        h[2] = (_Float16)a0.z; h[3] = (_Float16)a0.w;
        h[4] = (_Float16)a1.x; h[5] = (_Float16)a1.y;
        h[6] = (_Float16)a1.z; h[7] = (_Float16)a1.w;
        int byte = row * (2 * K) + kc * 16;
        byte ^= ((row & 7) << 4);
        *(f16x8*)((char*)A + byte) = h;
    }
    __syncthreads();

    const int wave = tid >> 6, lane = tid & 63;
    const int c0 = wave * CPW;
    const int lr = lane & 15;
    const int kg = lane >> 4;

    f32x4 acc[4][NFRAG];
#pragma unroll
    for (int m = 0; m < 4; ++m)
#pragma unroll
        for (int n = 0; n < NFRAG; ++n) acc[m][n] = (f32x4){0.f, 0.f, 0.f, 0.f};

    for (int ks = 0; ks < KSTEPS; ++ks) {
        const int k0 = ks * 32 + kg * 8;
        f16x8 af[4];
#pragma unroll
        for (int m = 0; m < 4; ++m) {
            int row = m * 16 + lr;
            int byte = row * (2 * K) + k0 * 2;
            byte ^= ((row & 7) << 4);
            af[m] = *(const f16x8*)((char*)A + byte);
        }
        f16x8 bf[NFRAG];
#pragma unroll
        for (int n = 0; n < NFRAG; ++n)
            bf[n] = *(const f16x8*)&PQWT[(size_t)(c0 + n * 16 + lr) * K + k0];
#pragma unroll
        for (int m = 0; m < 4; ++m)
#pragma unroll
            for (int n = 0; n < NFRAG; ++n)
                acc[m][n] = __builtin_amdgcn_mfma_f32_16x16x32_f16(af[m], bf[n], acc[m][n], 0, 0, 0);
    }

#pragma unroll
    for (int m = 0; m < 4; ++m)
#pragma unroll
        for (int n = 0; n < NFRAG; ++n) {
            int col = c0 + n * 16 + lr;
            float pbv = pb[col], bexv = bex[col];
            int row0 = m * 16 + kg * 4;
#pragma unroll
            for (int j = 0; j < 4; ++j) {
                int row = row0 + j;
                int node = n0 + row;
                if (node < nNodes) {
                    float v = acc[m][n][j] + (float)sdeg[row] * pbv + bexv;
                    if (col < HOUT) Ph[(size_t)node * HOUT + col] = (_Float16)v;
                    else            Qh[(size_t)node * HOUT + col - HOUT] = (_Float16)v;
                }
            }
        }
}

// ---------------------------------------------------------------------------
// Unified edge kernel (all convs): T=64, 4 waves, one tile per block.
//   A f16 swizzled in LDS; B streamed from L2 with 2-deep ping-pong prefetch
//   (static bfA/bfB names -> registers, loads issued under prior MFMAs);
//   in-register ballot segmented reduce.
// ---------------------------------------------------------------------------
template<int H>
__global__ __launch_bounds__(256, 4) void edge_reg(
    const _Float16* __restrict__ P, const _Float16* __restrict__ Q,
    const int* __restrict__ ssrc, const int* __restrict__ sdst,
    const _Float16* __restrict__ W2T, const float* __restrict__ b2,
    float* __restrict__ h2sum, int nE)
{
    constexpr int T = 64;
    constexpr int KCH = H / 8;             // f16x8 chunks per row
    constexpr int ITER = (T * KCH) / 256;  // staging chunks per thread
    constexpr int NFRAG = H / 64;          // 16-col fragments per wave
    constexpr int KSTEPS = H / 32;
    static_assert(H % 64 == 0 && ITER >= 1 && KSTEPS >= 2, "geometry");

    __shared__ _Float16 A[T * H];
    __shared__ int s_dst[T];
    __shared__ int s_src[T];

    // bijective XCD-chunked swizzle (consecutive dst ranges -> same XCD L2)
    int bid;
    {
        int b = blockIdx.x, nb = gridDim.x;
        int q = nb >> 3, r = nb & 7;
        int xcd = b & 7, idx = b >> 3;
        bid = (xcd < r) ? xcd * (q + 1) + idx
                        : r * (q + 1) + (xcd - r) * q + idx;
    }

    const int tid = threadIdx.x;
    const int e0 = bid * T;
    int nvalid = nE - e0; if (nvalid > T) nvalid = T;

    if (tid < T) { int e = e0 + tid; s_dst[tid] = (e < nE) ? sdst[e] : sdst[nE - 1]; }
    else if (tid < 2 * T) { int e = e0 + tid - T; s_src[tid - T] = (e < nE) ? ssrc[e] : 0; }
    __syncthreads();

    // gather + h1 = relu(P[dst]+Q[src]) -> swizzled A (short register liveness)
#pragma unroll
    for (int it = 0; it < ITER; ++it) {
        int q = tid + it * 256;
        int row = q / KCH, kc = q % KCH;
        f16x8 pv = *(const f16x8*)&P[(size_t)s_dst[row] * H + kc * 8];
        f16x8 qv = *(const f16x8*)&Q[(size_t)s_src[row] * H + kc * 8];
        f16x8 h;
#pragma unroll
        for (int j = 0; j < 8; ++j) {
            _Float16 v = pv[j] + qv[j];
            h[j] = v > (_Float16)0.f ? v : (_Float16)0.f;
        }
        int byte = row * (2 * H) + kc * 16;
        byte ^= ((row & 7) << 4);
        *(f16x8*)((char*)A + byte) = h;
    }
    __syncthreads();

    const int wave = tid >> 6, lane = tid & 63;
    const int c0 = wave * (H / 4);
    const int lr = lane & 15;
    const int kg = lane >> 4;

    // MFMA: h2_pre = h1 @ W2 + b2, with 2-deep B prefetch (bfA/bfB ping-pong)
    f32x4 acc[4][NFRAG];
#pragma unroll
    for (int n = 0; n < NFRAG; ++n) {
        float bv = b2[c0 + n * 16 + lr];
#pragma unroll
        for (int m = 0; m < 4; ++m) acc[m][n] = (f32x4){bv, bv, bv, bv};
    }

    f16x8 bfA[NFRAG], bfB[NFRAG];
#pragma unroll
    for (int n = 0; n < NFRAG; ++n)
        bfA[n] = *(const f16x8*)&W2T[(size_t)(c0 + n * 16 + lr) * H + kg * 8];
#pragma unroll
    for (int n = 0; n < NFRAG; ++n)
        bfB[n] = *(const f16x8*)&W2T[(size_t)(c0 + n * 16 + lr) * H + 32 + kg * 8];

#pragma unroll
    for (int ks = 0; ks < KSTEPS; ++ks) {
        const int k0 = ks * 32 + kg * 8;
        f16x8 af[4];
#pragma unroll
        for (int m = 0; m < 4; ++m) {
            int row = m * 16 + lr;
            int byte = row * (2 * H) + k0 * 2;
            byte ^= ((row & 7) << 4);
            af[m] = *(const f16x8*)((const char*)A + byte);
        }
        if ((ks & 1) == 0) {
#pragma unroll
            for (int m = 0; m < 4; ++m)
#pragma unroll
                for (int n = 0; n < NFRAG; ++n)
                    acc[m][n] = __builtin_amdgcn_mfma_f32_16x16x32_f16(af[m], bfA[n], acc[m][n], 0, 0, 0);
            if (ks + 2 < KSTEPS) {
#pragma unroll
                for (int n = 0; n < NFRAG; ++n)
                    bfA[n] = *(const f16x8*)&W2T[(size_t)(c0 + n * 16 + lr) * H + (ks + 2) * 32 + kg * 8];
            }
        } else {
#pragma unroll
            for (int m = 0; m < 4; ++m)
#pragma unroll
                for (int n = 0; n < NFRAG; ++n)
                    acc[m][n] = __builtin_amdgcn_mfma_f32_16x16x32_f16(af[m], bfB[n], acc[m][n], 0, 0, 0);
            if (ks + 2 < KSTEPS) {
#pragma unroll
                for (int n = 0; n < NFRAG; ++n)
                    bfB[n] = *(const f16x8*)&W2T[(size_t)(c0 + n * 16 + lr) * H + (ks + 2) * 32 + kg * 8];
            }
        }
    }

    // hoisted relu (once, not per segment)
#pragma unroll
    for (int m = 0; m < 4; ++m)
#pragma unroll
        for (int n = 0; n < NFRAG; ++n)
#pragma unroll
            for (int j = 0; j < 4; ++j)
                acc[m][n][j] = fmaxf(acc[m][n][j], 0.f);

    // segment boundary mask (wave-uniform)
    unsigned long long mask;
    {
        int t = lane;
        int dt = s_dst[t];
        int dn = s_dst[(t + 1) & 63];
        bool last = (t + 1 >= nvalid) || (dt != dn);
        mask = __ballot(last);
    }

    int r = 0;
    while (r < nvalid) {
        unsigned long long m2 = mask >> r;
        int len = (int)__ffsll((long long)m2);   // 1-based first set bit
        int rend = r + len;                       // segment = [r, rend)
        int d = s_dst[r];

        float part[NFRAG];
#pragma unroll
        for (int n = 0; n < NFRAG; ++n) part[n] = 0.f;

#pragma unroll
        for (int m = 0; m < 4; ++m) {
            int mlo = m * 16, mhi = mlo + 16;
            if (rend <= mlo || r >= mhi) continue;        // uniform skip
            if (r <= mlo && rend >= mhi) {                // fully inside: plain adds
#pragma unroll
                for (int n = 0; n < NFRAG; ++n)
#pragma unroll
                    for (int j = 0; j < 4; ++j)
                        part[n] += acc[m][n][j];
            } else {                                      // boundary block: predicated
#pragma unroll
                for (int j = 0; j < 4; ++j) {
                    int row = mlo + kg * 4 + j;
                    bool in = (row >= r) && (row < rend);
#pragma unroll
                    for (int n = 0; n < NFRAG; ++n)
                        part[n] += in ? acc[m][n][j] : 0.f;
                }
            }
        }
#pragma unroll
        for (int n = 0; n < NFRAG; ++n) {
            part[n] += __shfl_xor(part[n], 16);
            part[n] += __shfl_xor(part[n], 32);
        }
        if (kg == 0) {
#pragma unroll
            for (int n = 0; n < NFRAG; ++n)
                atomicAdd(&h2sum[(size_t)d * H + c0 + n * 16 + lr], part[n]);
        }
        r = rend;
    }
}

// ---------------------------------------------------------------------------
// Parallel pool: 40 nodes per block, segmented by (sorted) batch, atomics.
// ---------------------------------------------------------------------------
__global__ __launch_bounds__(256) void pool_part(
    const float* __restrict__ h2s3, const int* __restrict__ batch,
    const int* __restrict__ cursor, float* __restrict__ gsumh,
    float* __restrict__ gcnt, float* __restrict__ gdeg, int nNodes)
{
    constexpr int NPB = 40;
    __shared__ int sb[NPB];
    int n0 = blockIdx.x * NPB;
    int nn = nNodes - n0; if (nn > NPB) nn = NPB;
    if (nn <= 0) return;
    if (threadIdx.x < nn) sb[threadIdx.x] = batch[n0 + threadIdx.x];
    __syncthreads();
    int c = threadIdx.x;
    int g = sb[0];
    float a = 0.f;
    for (int i = 0; i < nn; ++i) {
        int gg = sb[i];
        if (gg != g) { atomicAdd(&gsumh[(size_t)g * 256 + c], a); a = 0.f; g = gg; }
        a += h2s3[(size_t)(n0 + i) * 256 + c];
    }
    atomicAdd(&gsumh[(size_t)g * 256 + c], a);
    if (c == 0) {
        int start = 0;
        for (int i = 1; i <= nn; ++i) {
            if (i == nn || sb[i] != sb[start]) {
                int gs = sb[start];
                atomicAdd(&gcnt[gs], (float)(i - start));
                int eEnd = cursor[n0 + i - 1];
                int eStart = (n0 + start > 0) ? cursor[n0 + start - 1] : 0;
                atomicAdd(&gdeg[gs], (float)(eEnd - eStart));
                start = i;
            }
        }
    }
}

// ---------------------------------------------------------------------------
// Head: one block per graph.
// ---------------------------------------------------------------------------
__global__ __launch_bounds__(256) void head64(
    const float* __restrict__ gsumh, const float* __restrict__ gcnt,
    const float* __restrict__ gdeg, const float* __restrict__ w3,
    const float* __restrict__ b3, const float* __restrict__ l2w,
    const float* __restrict__ l2b, const float* __restrict__ l3w,
    const float* __restrict__ l3b, float* __restrict__ out)
{
    __shared__ float gh[256];
    __shared__ float gm[256];
    __shared__ float hp[4][64];
    __shared__ float hv[64];
    int g = blockIdx.x, tid = threadIdx.x;
    gh[tid] = gsumh[(size_t)g * 256 + tid];
    __syncthreads();
    float dg = gdeg[g], cnt = fmaxf(gcnt[g], 1.f);
    float acc = dg * b3[tid];
#pragma unroll 4
    for (int k = 0; k < 256; ++k) acc += gh[k] * w3[(size_t)k * 256 + tid];
    gm[tid] = acc / cnt;
    __syncthreads();
    int c = tid & 63, q = tid >> 6;
    float a2 = 0.f;
#pragma unroll 4
    for (int kk = 0; kk < 64; ++kk) {
        int k = q * 64 + kk;
        a2 += gm[k] * l2w[(size_t)k * 64 + c];
    }
    hp[q][c] = a2;
    __syncthreads();
    if (tid < 64) hv[tid] = hp[0][tid] + hp[1][tid] + hp[2][tid] + hp[3][tid] + l2b[tid];
    __syncthreads();
    if (tid < 2) {
        float a3 = l3b[tid];
#pragma unroll 4
        for (int k = 0; k < 64; ++k) a3 += hv[k] * l3w[k * 2 + tid];
        out[g * 2 + tid] = 1.f / (1.f + expf(-a3));
    }
}

// ---------------------------------------------------------------------------
extern "C" void kernel_launch(void* const* d_in, const int* in_sizes, int n_in,
                              void* d_out, int out_size, void* d_ws, size_t ws_size,
                              hipStream_t stream)
{
    const float* x     = (const float*)d_in[0];
    const int*   ei    = (const int*)d_in[1];
    const int*   batch = (const int*)d_in[2];
    const float* c1_w1 = (const float*)d_in[3];
    const float* c1_b1 = (const float*)d_in[4];
    const float* c1_w2 = (const float*)d_in[5];
    const float* c1_b2 = (const float*)d_in[6];
    const float* c1_w3 = (const float*)d_in[7];
    const float* c1_b3 = (const float*)d_in[8];
    const float* c2_w1 = (const float*)d_in[9];
    const float* c2_b1 = (const float*)d_in[10];
    const float* c2_w2 = (const float*)d_in[11];
    const float* c2_b2 = (const float*)d_in[12];
    const float* c2_w3 = (const float*)d_in[13];
    const float* c2_b3 = (const float*)d_in[14];
    const float* c3_w1 = (const float*)d_in[15];
    const float* c3_b1 = (const float*)d_in[16];
    const float* c3_w2 = (const float*)d_in[17];
    const float* c3_b2 = (const float*)d_in[18];
    const float* c3_w3 = (const float*)d_in[19];
    const float* c3_b3 = (const float*)d_in[20];
    const float* l2w   = (const float*)d_in[21];
    const float* l2b   = (const float*)d_in[22];
    const float* l3w   = (const float*)d_in[23];
    const float* l3b   = (const float*)d_in[24];
    float* out = (float*)d_out;

    const int N = in_sizes[0] / 3;
    const int E = in_sizes[1] / 2;
    const int* src = ei;
    const int* dst = ei + E;

    // workspace layout — zeroed region first
    float* h2s1 = (float*)d_ws;                          // N*64
    float* h2s2 = h2s1 + (size_t)N * 64;                 // N*128
    float* h2s3 = h2s2 + (size_t)N * 128;                // N*256
    int*   hist = (int*)(h2s3 + (size_t)N * 256);        // N (deg)
    float* gsumh = (float*)(hist + N);                   // 64*256
    float* gcnt  = gsumh + (size_t)N_GRAPHS * 256;       // 64
    float* gdeg  = gcnt + N_GRAPHS;                      // 64  -- zero ends here
    int*   cursor = (int*)(gdeg + N_GRAPHS);             // N
    int*   ssrcb  = cursor + N;                          // E
    int*   sdstb  = ssrcb + E;                           // E
    _Float16* Ph  = (_Float16*)(sdstb + E);              // N*256 f16 (max H)
    _Float16* Qh  = Ph + (size_t)N * 256;                // N*256 f16
    _Float16* wt1 = Qh + (size_t)N * 256;                // 64*64 f16
    _Float16* wt2 = wt1 + 64 * 64;                       // 128*128 f16
    _Float16* wt3 = wt2 + 128 * 128;                     // 256*256 f16
    _Float16* pqwt2 = wt3 + 256 * 256;                   // 256*64 f16
    _Float16* pqwt3 = pqwt2 + 256 * 64;                  // 512*128 f16
    float* pb2   = (float*)(pqwt3 + 512 * 128);          // 256
    float* bex2  = pb2 + 256;                            // 256
    float* pb3   = bex2 + 256;                           // 512
    float* bex3  = pb3 + 512;                            // 512

    size_t zero_bytes = (size_t)N * (64 + 128 + 256) * sizeof(float)
                      + (size_t)N * sizeof(int)
                      + ((size_t)N_GRAPHS * 256 + 2 * N_GRAPHS) * sizeof(float);
    hipMemsetAsync(h2s1, 0, zero_bytes, stream);

    // sort edges by dst
    build_hist<<<(E + 255) / 256, 256, 0, stream>>>(dst, hist, E);
    scan_deg<<<1, 1024, 0, stream>>>(hist, cursor, N);
    scatter_edges<<<(E + 255) / 256, 256, 0, stream>>>(src, dst, cursor, ssrcb, sdstb, E);

    // all weight prep in ONE kernel (independent of node data)
    // total flat work = 4096+16384+65536+16384+65536+256+512 = 168704
    prep_all<<<(168704 + 255) / 256, 256, 0, stream>>>(
        c1_w2, c2_w2, c3_w2, c1_w3, c2_w1, c1_b3, c2_b1,
        c2_w3, c3_w1, c2_b3, c3_b1,
        wt1, wt2, wt3, pqwt2, pqwt3, pb2, bex2, pb3, bex3);

    const int ntiles = (E + 63) / 64;
    const int NB = (N + 63) / 64;

    // conv1: 3 -> 64
    node_pqh<3, 64><<<(N * 8 + 255) / 256, 256, 0, stream>>>(x, c1_w1, c1_b1, Ph, Qh, N);
    edge_reg<64><<<ntiles, 256, 0, stream>>>(Ph, Qh, ssrcb, sdstb, wt1, c1_b2, h2s1, E);

    // conv2: 64 -> 128
    pq_gemm<64, 128><<<NB, 256, 0, stream>>>(h2s1, pqwt2, pb2, bex2, hist, Ph, Qh, N);
    edge_reg<128><<<ntiles, 256, 0, stream>>>(Ph, Qh, ssrcb, sdstb, wt2, c2_b2, h2s2, E);

    // conv3: 128 -> 256
    pq_gemm<128, 256><<<NB, 256, 0, stream>>>(h2s2, pqwt3, pb3, bex3, hist, Ph, Qh, N);
    edge_reg<256><<<ntiles, 256, 0, stream>>>(Ph, Qh, ssrcb, sdstb, wt3, c3_b2, h2s3, E);

    // pool + head
    pool_part<<<(N + 39) / 40, 256, 0, stream>>>(h2s3, batch, cursor, gsumh, gcnt, gdeg, N);
    head64<<<N_GRAPHS, 256, 0, stream>>>(gsumh, gcnt, gdeg, c3_w3, c3_b3, l2w, l2b, l3w, l3b, out);
}

// Round 13
// 287.698 us; speedup vs baseline: 1.2422x; 1.0005x over previous
//
#include <hip/hip_runtime.h>
#include <cmath>

#define N_GRAPHS 64

typedef _Float16 f16x8 __attribute__((ext_vector_type(8)));
typedef _Float16 f16x4 __attribute__((ext_vector_type(4)));
typedef float f32x4 __attribute__((ext_vector_type(4)));

// ---------------------------------------------------------------------------
// Counting sort of edges by dst
// ---------------------------------------------------------------------------
__global__ __launch_bounds__(256) void build_hist(
    const int* __restrict__ dst, int* __restrict__ hist, int E)
{
    int i = blockIdx.x * 256 + threadIdx.x;
    if (i < E) atomicAdd(&hist[dst[i]], 1);
}

__global__ __launch_bounds__(1024) void scan_deg(
    const int* __restrict__ hist, int* __restrict__ cursor, int N)
{
    __shared__ int part[1024];
    int tid = threadIdx.x;
    int per = (N + 1023) / 1024;
    int base = tid * per;
    int s = 0;
    for (int i = 0; i < per; ++i) { int idx = base + i; if (idx < N) s += hist[idx]; }
    part[tid] = s;
    __syncthreads();
    for (int off = 1; off < 1024; off <<= 1) {
        int v = (tid >= off) ? part[tid - off] : 0;
        __syncthreads();
        part[tid] += v;
        __syncthreads();
    }
    int run = part[tid] - s;
    for (int i = 0; i < per; ++i) {
        int idx = base + i;
        if (idx < N) { cursor[idx] = run; run += hist[idx]; }
    }
}

__global__ __launch_bounds__(256) void scatter_edges(
    const int* __restrict__ src, const int* __restrict__ dst,
    int* __restrict__ cursor, int* __restrict__ ssrc, int* __restrict__ sdst, int E)
{
    int i = blockIdx.x * 256 + threadIdx.x;
    if (i >= E) return;
    int d = dst[i];
    int pos = atomicAdd(&cursor[d], 1);
    ssrc[pos] = src[i];
    sdst[pos] = d;
}

// ---------------------------------------------------------------------------
// ONE fused weight-prep kernel
// ---------------------------------------------------------------------------
__global__ __launch_bounds__(256) void prep_all(
    const float* __restrict__ c1w2, const float* __restrict__ c2w2,
    const float* __restrict__ c3w2, const float* __restrict__ c1w3,
    const float* __restrict__ c2w1, const float* __restrict__ c1b3,
    const float* __restrict__ c2b1, const float* __restrict__ c2w3,
    const float* __restrict__ c3w1, const float* __restrict__ c2b3,
    const float* __restrict__ c3b1,
    _Float16* __restrict__ wt1, _Float16* __restrict__ wt2,
    _Float16* __restrict__ wt3, _Float16* __restrict__ pqwt2,
    _Float16* __restrict__ pqwt3, float* __restrict__ pb2,
    float* __restrict__ bex2, float* __restrict__ pb3,
    float* __restrict__ bex3)
{
    int idx = blockIdx.x * 256 + threadIdx.x;
    if (idx < 4096) {                       // wt1: c1_w2^T (64x64)
        int n = idx >> 6, k = idx & 63;
        wt1[idx] = (_Float16)c1w2[k * 64 + n];
        return;
    }
    idx -= 4096;
    if (idx < 16384) {                      // wt2: c2_w2^T (128x128)
        int n = idx >> 7, k = idx & 127;
        wt2[idx] = (_Float16)c2w2[k * 128 + n];
        return;
    }
    idx -= 16384;
    if (idx < 65536) {                      // wt3: c3_w2^T (256x256)
        int n = idx >> 8, k = idx & 255;
        wt3[idx] = (_Float16)c3w2[k * 256 + n];
        return;
    }
    idx -= 65536;
    if (idx < 16384) {                      // pqwt2
        int j = idx >> 6, k = idx & 63;
        float acc = 0.f;
        if (j < 128) {
            for (int m = 0; m < 64; ++m)
                acc += c1w3[k * 64 + m] * (c2w1[m * 128 + j] - c2w1[(64 + m) * 128 + j]);
        } else {
            int jq = j - 128;
            for (int m = 0; m < 64; ++m)
                acc += c1w3[k * 64 + m] * c2w1[(64 + m) * 128 + jq];
        }
        pqwt2[idx] = (_Float16)acc;
        return;
    }
    idx -= 16384;
    if (idx < 65536) {                      // pqwt3
        int j = idx >> 7, k = idx & 127;
        float acc = 0.f;
        if (j < 256) {
            for (int m = 0; m < 128; ++m)
                acc += c2w3[k * 128 + m] * (c3w1[m * 256 + j] - c3w1[(128 + m) * 256 + j]);
        } else {
            int jq = j - 256;
            for (int m = 0; m < 128; ++m)
                acc += c2w3[k * 128 + m] * c3w1[(128 + m) * 256 + jq];
        }
        pqwt3[idx] = (_Float16)acc;
        return;
    }
    idx -= 65536;
    if (idx < 256) {                        // pb2/bex2
        int j = idx;
        float acc = 0.f;
        if (j < 128) {
            for (int m = 0; m < 64; ++m)
                acc += c1b3[m] * (c2w1[m * 128 + j] - c2w1[(64 + m) * 128 + j]);
            bex2[j] = c2b1[j];
        } else {
            int jq = j - 128;
            for (int m = 0; m < 64; ++m)
                acc += c1b3[m] * c2w1[(64 + m) * 128 + jq];
            bex2[j] = 0.f;
        }
        pb2[j] = acc;
        return;
    }
    idx -= 256;
    if (idx < 512) {                        // pb3/bex3
        int j = idx;
        float acc = 0.f;
        if (j < 256) {
            for (int m = 0; m < 128; ++m)
                acc += c2b3[m] * (c3w1[m * 256 + j] - c3w1[(128 + m) * 256 + j]);
            bex3[j] = c3b1[j];
        } else {
            int jq = j - 256;
            for (int m = 0; m < 128; ++m)
                acc += c2b3[m] * c3w1[(128 + m) * 256 + jq];
            bex3[j] = 0.f;
        }
        pb3[j] = acc;
        return;
    }
}

// ---------------------------------------------------------------------------
// conv1 P/Q from raw x (F=3)
// ---------------------------------------------------------------------------
template<int F, int H>
__global__ __launch_bounds__(256) void node_pqh(
    const float* __restrict__ x, const float* __restrict__ w1,
    const float* __restrict__ b1, _Float16* __restrict__ P,
    _Float16* __restrict__ Q, int nNodes)
{
    int idx = blockIdx.x * 256 + threadIdx.x;
    int total = nNodes * (H / 8);
    if (idx >= total) return;
    int n = idx / (H / 8), j8 = (idx % (H / 8)) * 8;
    float p[8], q[8];
#pragma unroll
    for (int j = 0; j < 8; ++j) { p[j] = b1[j8 + j]; q[j] = 0.f; }
    for (int k = 0; k < F; ++k) {
        float xv = x[(size_t)n * F + k];
        const float* wt = &w1[(size_t)k * H + j8];
        const float* wb = &w1[(size_t)(F + k) * H + j8];
        float4 t0 = *(const float4*)wt, t1 = *(const float4*)(wt + 4);
        float4 b0 = *(const float4*)wb, b1v = *(const float4*)(wb + 4);
        p[0] += xv * (t0.x - b0.x);  q[0] += xv * b0.x;
        p[1] += xv * (t0.y - b0.y);  q[1] += xv * b0.y;
        p[2] += xv * (t0.z - b0.z);  q[2] += xv * b0.z;
        p[3] += xv * (t0.w - b0.w);  q[3] += xv * b0.w;
        p[4] += xv * (t1.x - b1v.x); q[4] += xv * b1v.x;
        p[5] += xv * (t1.y - b1v.y); q[5] += xv * b1v.y;
        p[6] += xv * (t1.z - b1v.z); q[6] += xv * b1v.z;
        p[7] += xv * (t1.w - b1v.w); q[7] += xv * b1v.w;
    }
    f16x8 ph, qh;
#pragma unroll
    for (int j = 0; j < 8; ++j) { ph[j] = (_Float16)p[j]; qh[j] = (_Float16)q[j]; }
    *(f16x8*)&P[(size_t)n * H + j8] = ph;
    *(f16x8*)&Q[(size_t)n * H + j8] = qh;
}

// ---------------------------------------------------------------------------
// pq_gemm: [P|Q](f16) = f16GEMM(h2sum_prev, PQWT) + deg*pb + bex
// ---------------------------------------------------------------------------
template<int K, int HOUT>
__global__ __launch_bounds__(256) void pq_gemm(
    const float* __restrict__ h2sum, const _Float16* __restrict__ PQWT,
    const float* __restrict__ pb, const float* __restrict__ bex,
    const int* __restrict__ deg, _Float16* __restrict__ Ph,
    _Float16* __restrict__ Qh, int nNodes)
{
    constexpr int T = 64;
    constexpr int KCH = K / 8;
    constexpr int CPW = (2 * HOUT) / 4;
    constexpr int NFRAG = CPW / 16;
    constexpr int KSTEPS = K / 32;

    __shared__ _Float16 A[T * K];
    __shared__ int sdeg[T];

    const int tid = threadIdx.x;
    const int n0 = blockIdx.x * T;

    if (tid < T) { int n = n0 + tid; sdeg[tid] = (n < nNodes) ? deg[n] : 0; }

    for (int q = tid; q < T * KCH; q += 256) {
        int row = q / KCH, kc = q % KCH;
        int n = n0 + row; if (n >= nNodes) n = nNodes - 1;
        const float* hr = h2sum + (size_t)n * K + kc * 8;
        float4 a0 = *(const float4*)hr, a1 = *(const float4*)(hr + 4);
        f16x8 h;
        h[0] = (_Float16)a0.x; h[1] = (_Float16)a0.y;
        h[2] = (_Float16)a0.z; h[3] = (_Float16)a0.w;
        h[4] = (_Float16)a1.x; h[5] = (_Float16)a1.y;
        h[6] = (_Float16)a1.z; h[7] = (_Float16)a1.w;
        int byte = row * (2 * K) + kc * 16;
        byte ^= ((row & 7) << 4);
        *(f16x8*)((char*)A + byte) = h;
    }
    __syncthreads();

    const int wave = tid >> 6, lane = tid & 63;
    const int c0 = wave * CPW;
    const int lr = lane & 15;
    const int kg = lane >> 4;

    f32x4 acc[4][NFRAG];
#pragma unroll
    for (int m = 0; m < 4; ++m)
#pragma unroll
        for (int n = 0; n < NFRAG; ++n) acc[m][n] = (f32x4){0.f, 0.f, 0.f, 0.f};

    for (int ks = 0; ks < KSTEPS; ++ks) {
        const int k0 = ks * 32 + kg * 8;
        f16x8 af[4];
#pragma unroll
        for (int m = 0; m < 4; ++m) {
            int row = m * 16 + lr;
            int byte = row * (2 * K) + k0 * 2;
            byte ^= ((row & 7) << 4);
            af[m] = *(const f16x8*)((char*)A + byte);
        }
        f16x8 bf[NFRAG];
#pragma unroll
        for (int n = 0; n < NFRAG; ++n)
            bf[n] = *(const f16x8*)&PQWT[(size_t)(c0 + n * 16 + lr) * K + k0];
#pragma unroll
        for (int m = 0; m < 4; ++m)
#pragma unroll
            for (int n = 0; n < NFRAG; ++n)
                acc[m][n] = __builtin_amdgcn_mfma_f32_16x16x32_f16(af[m], bf[n], acc[m][n], 0, 0, 0);
    }

#pragma unroll
    for (int m = 0; m < 4; ++m)
#pragma unroll
        for (int n = 0; n < NFRAG; ++n) {
            int col = c0 + n * 16 + lr;
            float pbv = pb[col], bexv = bex[col];
            int row0 = m * 16 + kg * 4;
#pragma unroll
            for (int j = 0; j < 4; ++j) {
                int row = row0 + j;
                int node = n0 + row;
                if (node < nNodes) {
                    float v = acc[m][n][j] + (float)sdeg[row] * pbv + bexv;
                    if (col < HOUT) Ph[(size_t)node * HOUT + col] = (_Float16)v;
                    else            Qh[(size_t)node * HOUT + col - HOUT] = (_Float16)v;
                }
            }
        }
}

// ---------------------------------------------------------------------------
// Unified edge kernel: T=64, 4 waves, one tile per block.
//   BATCHED gather: issue ALL P/Q loads first (concurrent in-flight),
//   then pack+write to swizzled LDS. Loads' liveness ends before acc is
//   born -> no cross-phase spill. B 2-deep ping-pong prefetch. In-register
//   ballot segmented reduce.
// ---------------------------------------------------------------------------
template<int H>
__global__ __launch_bounds__(256, 4) void edge_reg(
    const _Float16* __restrict__ P, const _Float16* __restrict__ Q,
    const int* __restrict__ ssrc, const int* __restrict__ sdst,
    const _Float16* __restrict__ W2T, const float* __restrict__ b2,
    float* __restrict__ h2sum, int nE)
{
    constexpr int T = 64;
    constexpr int KCH = H / 8;             // f16x8 chunks per row
    constexpr int ITER = (T * KCH) / 256;  // staging chunks per thread
    constexpr int NFRAG = H / 64;          // 16-col fragments per wave
    constexpr int KSTEPS = H / 32;
    static_assert(H % 64 == 0 && ITER >= 1 && KSTEPS >= 2, "geometry");

    __shared__ _Float16 A[T * H];
    __shared__ int s_dst[T];
    __shared__ int s_src[T];

    // bijective XCD-chunked swizzle (consecutive dst ranges -> same XCD L2)
    int bid;
    {
        int b = blockIdx.x, nb = gridDim.x;
        int q = nb >> 3, r = nb & 7;
        int xcd = b & 7, idx = b >> 3;
        bid = (xcd < r) ? xcd * (q + 1) + idx
                        : r * (q + 1) + (xcd - r) * q + idx;
    }

    const int tid = threadIdx.x;
    const int e0 = bid * T;
    int nvalid = nE - e0; if (nvalid > T) nvalid = T;

    if (tid < T) { int e = e0 + tid; s_dst[tid] = (e < nE) ? sdst[e] : sdst[nE - 1]; }
    else if (tid < 2 * T) { int e = e0 + tid - T; s_src[tid - T] = (e < nE) ? ssrc[e] : 0; }
    __syncthreads();

    // ---- BATCHED gather: all loads in flight, then pack+write ----
    {
        f16x8 pv[ITER], qv[ITER];
#pragma unroll
        for (int it = 0; it < ITER; ++it) {
            int q = tid + it * 256;
            int row = q / KCH, kc = q % KCH;
            pv[it] = *(const f16x8*)&P[(size_t)s_dst[row] * H + kc * 8];
            qv[it] = *(const f16x8*)&Q[(size_t)s_src[row] * H + kc * 8];
        }
#pragma unroll
        for (int it = 0; it < ITER; ++it) {
            int q = tid + it * 256;
            int row = q / KCH, kc = q % KCH;
            f16x8 h;
#pragma unroll
            for (int j = 0; j < 8; ++j) {
                _Float16 v = pv[it][j] + qv[it][j];
                h[j] = v > (_Float16)0.f ? v : (_Float16)0.f;
            }
            int byte = row * (2 * H) + kc * 16;
            byte ^= ((row & 7) << 4);
            *(f16x8*)((char*)A + byte) = h;
        }
    }
    __syncthreads();

    const int wave = tid >> 6, lane = tid & 63;
    const int c0 = wave * (H / 4);
    const int lr = lane & 15;
    const int kg = lane >> 4;

    // MFMA: h2_pre = h1 @ W2 + b2, with 2-deep B prefetch (bfA/bfB ping-pong)
    f32x4 acc[4][NFRAG];
#pragma unroll
    for (int n = 0; n < NFRAG; ++n) {
        float bv = b2[c0 + n * 16 + lr];
#pragma unroll
        for (int m = 0; m < 4; ++m) acc[m][n] = (f32x4){bv, bv, bv, bv};
    }

    f16x8 bfA[NFRAG], bfB[NFRAG];
#pragma unroll
    for (int n = 0; n < NFRAG; ++n)
        bfA[n] = *(const f16x8*)&W2T[(size_t)(c0 + n * 16 + lr) * H + kg * 8];
#pragma unroll
    for (int n = 0; n < NFRAG; ++n)
        bfB[n] = *(const f16x8*)&W2T[(size_t)(c0 + n * 16 + lr) * H + 32 + kg * 8];

#pragma unroll
    for (int ks = 0; ks < KSTEPS; ++ks) {
        const int k0 = ks * 32 + kg * 8;
        f16x8 af[4];
#pragma unroll
        for (int m = 0; m < 4; ++m) {
            int row = m * 16 + lr;
            int byte = row * (2 * H) + k0 * 2;
            byte ^= ((row & 7) << 4);
            af[m] = *(const f16x8*)((const char*)A + byte);
        }
        if ((ks & 1) == 0) {
#pragma unroll
            for (int m = 0; m < 4; ++m)
#pragma unroll
                for (int n = 0; n < NFRAG; ++n)
                    acc[m][n] = __builtin_amdgcn_mfma_f32_16x16x32_f16(af[m], bfA[n], acc[m][n], 0, 0, 0);
            if (ks + 2 < KSTEPS) {
#pragma unroll
                for (int n = 0; n < NFRAG; ++n)
                    bfA[n] = *(const f16x8*)&W2T[(size_t)(c0 + n * 16 + lr) * H + (ks + 2) * 32 + kg * 8];
            }
        } else {
#pragma unroll
            for (int m = 0; m < 4; ++m)
#pragma unroll
                for (int n = 0; n < NFRAG; ++n)
                    acc[m][n] = __builtin_amdgcn_mfma_f32_16x16x32_f16(af[m], bfB[n], acc[m][n], 0, 0, 0);
            if (ks + 2 < KSTEPS) {
#pragma unroll
                for (int n = 0; n < NFRAG; ++n)
                    bfB[n] = *(const f16x8*)&W2T[(size_t)(c0 + n * 16 + lr) * H + (ks + 2) * 32 + kg * 8];
            }
        }
    }

    // hoisted relu (once, not per segment)
#pragma unroll
    for (int m = 0; m < 4; ++m)
#pragma unroll
        for (int n = 0; n < NFRAG; ++n)
#pragma unroll
            for (int j = 0; j < 4; ++j)
                acc[m][n][j] = fmaxf(acc[m][n][j], 0.f);

    // segment boundary mask (wave-uniform)
    unsigned long long mask;
    {
        int t = lane;
        int dt = s_dst[t];
        int dn = s_dst[(t + 1) & 63];
        bool last = (t + 1 >= nvalid) || (dt != dn);
        mask = __ballot(last);
    }

    int r = 0;
    while (r < nvalid) {
        unsigned long long m2 = mask >> r;
        int len = (int)__ffsll((long long)m2);   // 1-based first set bit
        int rend = r + len;                       // segment = [r, rend)
        int d = s_dst[r];

        float part[NFRAG];
#pragma unroll
        for (int n = 0; n < NFRAG; ++n) part[n] = 0.f;

#pragma unroll
        for (int m = 0; m < 4; ++m) {
            int mlo = m * 16, mhi = mlo + 16;
            if (rend <= mlo || r >= mhi) continue;        // uniform skip
            if (r <= mlo && rend >= mhi) {                // fully inside: plain adds
#pragma unroll
                for (int n = 0; n < NFRAG; ++n)
#pragma unroll
                    for (int j = 0; j < 4; ++j)
                        part[n] += acc[m][n][j];
            } else {                                      // boundary block: predicated
#pragma unroll
                for (int j = 0; j < 4; ++j) {
                    int row = mlo + kg * 4 + j;
                    bool in = (row >= r) && (row < rend);
#pragma unroll
                    for (int n = 0; n < NFRAG; ++n)
                        part[n] += in ? acc[m][n][j] : 0.f;
                }
            }
        }
#pragma unroll
        for (int n = 0; n < NFRAG; ++n) {
            part[n] += __shfl_xor(part[n], 16);
            part[n] += __shfl_xor(part[n], 32);
        }
        if (kg == 0) {
#pragma unroll
            for (int n = 0; n < NFRAG; ++n)
                atomicAdd(&h2sum[(size_t)d * H + c0 + n * 16 + lr], part[n]);
        }
        r = rend;
    }
}

// ---------------------------------------------------------------------------
// Parallel pool: 40 nodes per block, segmented by (sorted) batch, atomics.
// ---------------------------------------------------------------------------
__global__ __launch_bounds__(256) void pool_part(
    const float* __restrict__ h2s3, const int* __restrict__ batch,
    const int* __restrict__ cursor, float* __restrict__ gsumh,
    float* __restrict__ gcnt, float* __restrict__ gdeg, int nNodes)
{
    constexpr int NPB = 40;
    __shared__ int sb[NPB];
    int n0 = blockIdx.x * NPB;
    int nn = nNodes - n0; if (nn > NPB) nn = NPB;
    if (nn <= 0) return;
    if (threadIdx.x < nn) sb[threadIdx.x] = batch[n0 + threadIdx.x];
    __syncthreads();
    int c = threadIdx.x;
    int g = sb[0];
    float a = 0.f;
    for (int i = 0; i < nn; ++i) {
        int gg = sb[i];
        if (gg != g) { atomicAdd(&gsumh[(size_t)g * 256 + c], a); a = 0.f; g = gg; }
        a += h2s3[(size_t)(n0 + i) * 256 + c];
    }
    atomicAdd(&gsumh[(size_t)g * 256 + c], a);
    if (c == 0) {
        int start = 0;
        for (int i = 1; i <= nn; ++i) {
            if (i == nn || sb[i] != sb[start]) {
                int gs = sb[start];
                atomicAdd(&gcnt[gs], (float)(i - start));
                int eEnd = cursor[n0 + i - 1];
                int eStart = (n0 + start > 0) ? cursor[n0 + start - 1] : 0;
                atomicAdd(&gdeg[gs], (float)(eEnd - eStart));
                start = i;
            }
        }
    }
}

// ---------------------------------------------------------------------------
// Head: one block per graph.
// ---------------------------------------------------------------------------
__global__ __launch_bounds__(256) void head64(
    const float* __restrict__ gsumh, const float* __restrict__ gcnt,
    const float* __restrict__ gdeg, const float* __restrict__ w3,
    const float* __restrict__ b3, const float* __restrict__ l2w,
    const float* __restrict__ l2b, const float* __restrict__ l3w,
    const float* __restrict__ l3b, float* __restrict__ out)
{
    __shared__ float gh[256];
    __shared__ float gm[256];
    __shared__ float hp[4][64];
    __shared__ float hv[64];
    int g = blockIdx.x, tid = threadIdx.x;
    gh[tid] = gsumh[(size_t)g * 256 + tid];
    __syncthreads();
    float dg = gdeg[g], cnt = fmaxf(gcnt[g], 1.f);
    float acc = dg * b3[tid];
#pragma unroll 4
    for (int k = 0; k < 256; ++k) acc += gh[k] * w3[(size_t)k * 256 + tid];
    gm[tid] = acc / cnt;
    __syncthreads();
    int c = tid & 63, q = tid >> 6;
    float a2 = 0.f;
#pragma unroll 4
    for (int kk = 0; kk < 64; ++kk) {
        int k = q * 64 + kk;
        a2 += gm[k] * l2w[(size_t)k * 64 + c];
    }
    hp[q][c] = a2;
    __syncthreads();
    if (tid < 64) hv[tid] = hp[0][tid] + hp[1][tid] + hp[2][tid] + hp[3][tid] + l2b[tid];
    __syncthreads();
    if (tid < 2) {
        float a3 = l3b[tid];
#pragma unroll 4
        for (int k = 0; k < 64; ++k) a3 += hv[k] * l3w[k * 2 + tid];
        out[g * 2 + tid] = 1.f / (1.f + expf(-a3));
    }
}

// ---------------------------------------------------------------------------
extern "C" void kernel_launch(void* const* d_in, const int* in_sizes, int n_in,
                              void* d_out, int out_size, void* d_ws, size_t ws_size,
                              hipStream_t stream)
{
    const float* x     = (const float*)d_in[0];
    const int*   ei    = (const int*)d_in[1];
    const int*   batch = (const int*)d_in[2];
    const float* c1_w1 = (const float*)d_in[3];
    const float* c1_b1 = (const float*)d_in[4];
    const float* c1_w2 = (const float*)d_in[5];
    const float* c1_b2 = (const float*)d_in[6];
    const float* c1_w3 = (const float*)d_in[7];
    const float* c1_b3 = (const float*)d_in[8];
    const float* c2_w1 = (const float*)d_in[9];
    const float* c2_b1 = (const float*)d_in[10];
    const float* c2_w2 = (const float*)d_in[11];
    const float* c2_b2 = (const float*)d_in[12];
    const float* c2_w3 = (const float*)d_in[13];
    const float* c2_b3 = (const float*)d_in[14];
    const float* c3_w1 = (const float*)d_in[15];
    const float* c3_b1 = (const float*)d_in[16];
    const float* c3_w2 = (const float*)d_in[17];
    const float* c3_b2 = (const float*)d_in[18];
    const float* c3_w3 = (const float*)d_in[19];
    const float* c3_b3 = (const float*)d_in[20];
    const float* l2w   = (const float*)d_in[21];
    const float* l2b   = (const float*)d_in[22];
    const float* l3w   = (const float*)d_in[23];
    const float* l3b   = (const float*)d_in[24];
    float* out = (float*)d_out;

    const int N = in_sizes[0] / 3;
    const int E = in_sizes[1] / 2;
    const int* src = ei;
    const int* dst = ei + E;

    // workspace layout — zeroed region first
    float* h2s1 = (float*)d_ws;                          // N*64
    float* h2s2 = h2s1 + (size_t)N * 64;                 // N*128
    float* h2s3 = h2s2 + (size_t)N * 128;                // N*256
    int*   hist = (int*)(h2s3 + (size_t)N * 256);        // N (deg)
    float* gsumh = (float*)(hist + N);                   // 64*256
    float* gcnt  = gsumh + (size_t)N_GRAPHS * 256;       // 64
    float* gdeg  = gcnt + N_GRAPHS;                      // 64  -- zero ends here
    int*   cursor = (int*)(gdeg + N_GRAPHS);             // N
    int*   ssrcb  = cursor + N;                          // E
    int*   sdstb  = ssrcb + E;                           // E
    _Float16* Ph  = (_Float16*)(sdstb + E);              // N*256 f16 (max H)
    _Float16* Qh  = Ph + (size_t)N * 256;                // N*256 f16
    _Float16* wt1 = Qh + (size_t)N * 256;                // 64*64 f16
    _Float16* wt2 = wt1 + 64 * 64;                       // 128*128 f16
    _Float16* wt3 = wt2 + 128 * 128;                     // 256*256 f16
    _Float16* pqwt2 = wt3 + 256 * 256;                   // 256*64 f16
    _Float16* pqwt3 = pqwt2 + 256 * 64;                  // 512*128 f16
    float* pb2   = (float*)(pqwt3 + 512 * 128);          // 256
    float* bex2  = pb2 + 256;                            // 256
    float* pb3   = bex2 + 256;                           // 512
    float* bex3  = pb3 + 512;                            // 512

    size_t zero_bytes = (size_t)N * (64 + 128 + 256) * sizeof(float)
                      + (size_t)N * sizeof(int)
                      + ((size_t)N_GRAPHS * 256 + 2 * N_GRAPHS) * sizeof(float);
    hipMemsetAsync(h2s1, 0, zero_bytes, stream);

    // sort edges by dst
    build_hist<<<(E + 255) / 256, 256, 0, stream>>>(dst, hist, E);
    scan_deg<<<1, 1024, 0, stream>>>(hist, cursor, N);
    scatter_edges<<<(E + 255) / 256, 256, 0, stream>>>(src, dst, cursor, ssrcb, sdstb, E);

    // all weight prep in ONE kernel (independent of node data)
    prep_all<<<(168704 + 255) / 256, 256, 0, stream>>>(
        c1_w2, c2_w2, c3_w2, c1_w3, c2_w1, c1_b3, c2_b1,
        c2_w3, c3_w1, c2_b3, c3_b1,
        wt1, wt2, wt3, pqwt2, pqwt3, pb2, bex2, pb3, bex3);

    const int ntiles = (E + 63) / 64;
    const int NB = (N + 63) / 64;

    // conv1: 3 -> 64
    node_pqh<3, 64><<<(N * 8 + 255) / 256, 256, 0, stream>>>(x, c1_w1, c1_b1, Ph, Qh, N);
    edge_reg<64><<<ntiles, 256, 0, stream>>>(Ph, Qh, ssrcb, sdstb, wt1, c1_b2, h2s1, E);

    // conv2: 64 -> 128
    pq_gemm<64, 128><<<NB, 256, 0, stream>>>(h2s1, pqwt2, pb2, bex2, hist, Ph, Qh, N);
    edge_reg<128><<<ntiles, 256, 0, stream>>>(Ph, Qh, ssrcb, sdstb, wt2, c2_b2, h2s2, E);

    // conv3: 128 -> 256
    pq_gemm<128, 256><<<NB, 256, 0, stream>>>(h2s2, pqwt3, pb3, bex3, hist, Ph, Qh, N);
    edge_reg<256><<<ntiles, 256, 0, stream>>>(Ph, Qh, ssrcb, sdstb, wt3, c3_b2, h2s3, E);

    // pool + head
    pool_part<<<(N + 39) / 40, 256, 0, stream>>>(h2s3, batch, cursor, gsumh, gcnt, gdeg, N);
    head64<<<N_GRAPHS, 256, 0, stream>>>(gsumh, gcnt, gdeg, c3_w3, c3_b3, l2w, l2b, l3w, l3b, out);
}